// Round 1
// baseline (583.556 us; speedup 1.0000x reference)
//
#include <hip/hip_runtime.h>

#define T_DIM 200
#define U_DIM 100
#define D_DIM 512
#define V_DIM 1024
#define TU_DIM (T_DIM * U_DIM)   // 20000
#define M_TOTAL (8 * TU_DIM)     // 160000 rows

#define M_TILE 64
#define N_TILE 128
#define K_STEP 64
#define A_LDW 520                // 512 + 8 bf16 pad  -> 2-way bank aliasing (free)
#define W_LDW 72                 // 64 + 8 bf16 pad

typedef __attribute__((ext_vector_type(8))) short bf16x8;
typedef __attribute__((ext_vector_type(4))) float f32x4;

__device__ __forceinline__ unsigned short f2bf(float f) {
    unsigned int u = __float_as_uint(f);
    u += 0x7FFFu + ((u >> 16) & 1u);   // RNE to bf16
    return (unsigned short)(u >> 16);
}

__device__ __forceinline__ float fast_tanh(float x) {
    // tanh(x) = 1 - 2/(exp(2x)+1); saturates correctly at +/-inf of exp
    float e = __expf(2.0f * x);
    return 1.0f - 2.0f / (e + 1.0f);
}

// ---- prep: convert joiner_w (V,D) f32 -> bf16 into workspace ----
__global__ void conv_w_kernel(const float* __restrict__ w, ushort4* __restrict__ wbf) {
    int i = blockIdx.x * blockDim.x + threadIdx.x;    // 131072 float4 chunks
    float4 v = reinterpret_cast<const float4*>(w)[i];
    ushort4 o;
    o.x = f2bf(v.x); o.y = f2bf(v.y); o.z = f2bf(v.z); o.w = f2bf(v.w);
    wbf[i] = o;
}

__global__ __launch_bounds__(512, 1)
void joiner_kernel(const float* __restrict__ enc,
                   const int* __restrict__ prefix,
                   const float* __restrict__ emb,
                   const unsigned short* __restrict__ wbf,
                   const float* __restrict__ bias,
                   float* __restrict__ out) {
    __shared__ unsigned short A_s[M_TILE * A_LDW];   // 66560 B
    __shared__ unsigned short W_s[N_TILE * W_LDW];   // 18432 B

    const int tid = threadIdx.x;
    const long long g0 = (long long)blockIdx.x * M_TILE;

    // ---------- Phase 1: A tile = bf16(tanh(enc_row + emb[prefix])) , full K ----------
    {
        const int r = tid >> 3;          // 0..63 : row within tile (8 threads/row)
        const int q = tid & 7;
        const int g = (int)g0 + r;       // global row
        const int b = g / TU_DIM;
        const int m = g - b * TU_DIM;
        const int t = m / U_DIM;
        const int u = m - t * U_DIM;
        const float* encp = enc + (size_t)(b * T_DIM + t) * D_DIM;
        const float* embp = emb + (size_t)prefix[b * U_DIM + u] * D_DIM;
#pragma unroll
        for (int jj = 0; jj < 8; ++jj) {
            const int d = q * 8 + jj * 64;
            float4 e0 = *reinterpret_cast<const float4*>(encp + d);
            float4 e1 = *reinterpret_cast<const float4*>(encp + d + 4);
            float4 p0 = *reinterpret_cast<const float4*>(embp + d);
            float4 p1 = *reinterpret_cast<const float4*>(embp + d + 4);
            bf16x8 pk;
            pk[0] = (short)f2bf(fast_tanh(e0.x + p0.x));
            pk[1] = (short)f2bf(fast_tanh(e0.y + p0.y));
            pk[2] = (short)f2bf(fast_tanh(e0.z + p0.z));
            pk[3] = (short)f2bf(fast_tanh(e0.w + p0.w));
            pk[4] = (short)f2bf(fast_tanh(e1.x + p1.x));
            pk[5] = (short)f2bf(fast_tanh(e1.y + p1.y));
            pk[6] = (short)f2bf(fast_tanh(e1.z + p1.z));
            pk[7] = (short)f2bf(fast_tanh(e1.w + p1.w));
            *reinterpret_cast<bf16x8*>(&A_s[r * A_LDW + d]) = pk;
        }
    }

    // ---------- Phase 2: C tile = A (LDS) x W^T, v-loop outer / k-loop inner ----------
    const int lane = tid & 63;
    const int wid  = tid >> 6;           // 8 waves: 2 (m) x 4 (n)
    const int wm   = (wid >> 2) * 32;
    const int wn   = (wid & 3) * 32;
    const int lr   = lane & 15;
    const int lg   = lane >> 4;

    uint4 wreg[2];
    auto load_w = [&](int v0, int k0) {
#pragma unroll
        for (int i = 0; i < 2; ++i) {
            int c   = tid + 512 * i;      // 1024 chunks of 16B
            int row = c >> 3;
            int k8  = (c & 7) * 8;
            wreg[i] = *reinterpret_cast<const uint4*>(wbf + (size_t)(v0 + row) * D_DIM + k0 + k8);
        }
    };
    auto store_w = [&]() {
#pragma unroll
        for (int i = 0; i < 2; ++i) {
            int c   = tid + 512 * i;
            int row = c >> 3;
            int k8  = (c & 7) * 8;
            *reinterpret_cast<uint4*>(&W_s[row * W_LDW + k8]) = wreg[i];
        }
    };

    load_w(0, 0);   // prefetch first stage (also overlaps Phase 1 tail)

    for (int vt = 0; vt < 8; ++vt) {
        const int v0 = vt * N_TILE;
        f32x4 acc[2][2];
#pragma unroll
        for (int mi = 0; mi < 2; ++mi)
#pragma unroll
            for (int ni = 0; ni < 2; ++ni)
                acc[mi][ni] = (f32x4){0.f, 0.f, 0.f, 0.f};

        for (int kt = 0; kt < 8; ++kt) {
            const int k0 = kt * K_STEP;
            __syncthreads();               // previous stage compute done
            store_w();
            if (!(vt == 7 && kt == 7)) {   // prefetch next stage into regs
                int nvt = vt, nk0 = k0 + K_STEP;
                if (kt == 7) { nvt = vt + 1; nk0 = 0; }
                load_w(nvt * N_TILE, nk0);
            }
            __syncthreads();               // W_s ready
#pragma unroll
            for (int kk = 0; kk < 2; ++kk) {
                const int kb  = k0 + kk * 32 + lg * 8;
                bf16x8 a0 = *reinterpret_cast<const bf16x8*>(&A_s[(wm + lr) * A_LDW + kb]);
                bf16x8 a1 = *reinterpret_cast<const bf16x8*>(&A_s[(wm + 16 + lr) * A_LDW + kb]);
                const int wkb = kk * 32 + lg * 8;
                bf16x8 b0 = *reinterpret_cast<const bf16x8*>(&W_s[(wn + lr) * W_LDW + wkb]);
                bf16x8 b1 = *reinterpret_cast<const bf16x8*>(&W_s[(wn + 16 + lr) * W_LDW + wkb]);
                acc[0][0] = __builtin_amdgcn_mfma_f32_16x16x32_bf16(a0, b0, acc[0][0], 0, 0, 0);
                acc[0][1] = __builtin_amdgcn_mfma_f32_16x16x32_bf16(a0, b1, acc[0][1], 0, 0, 0);
                acc[1][0] = __builtin_amdgcn_mfma_f32_16x16x32_bf16(a1, b0, acc[1][0], 0, 0, 0);
                acc[1][1] = __builtin_amdgcn_mfma_f32_16x16x32_bf16(a1, b1, acc[1][1], 0, 0, 0);
            }
        }

        // epilogue: C rows are contiguous in v; add bias
        float bv0 = bias[v0 + wn + lr];
        float bv1 = bias[v0 + wn + 16 + lr];
#pragma unroll
        for (int mi = 0; mi < 2; ++mi) {
#pragma unroll
            for (int j = 0; j < 4; ++j) {
                const long long row = g0 + wm + mi * 16 + lg * 4 + j;
                float* op = out + row * V_DIM + v0 + wn;
                op[lr]      = acc[mi][0][j] + bv0;
                op[16 + lr] = acc[mi][1][j] + bv1;
            }
        }
    }
}

extern "C" void kernel_launch(void* const* d_in, const int* in_sizes, int n_in,
                              void* d_out, int out_size, void* d_ws, size_t ws_size,
                              hipStream_t stream) {
    const float* enc    = (const float*)d_in[0];   // (8,200,512) f32
    const int*   prefix = (const int*)d_in[1];     // (8,100) int
    const float* emb    = (const float*)d_in[2];   // (1024,512) f32
    const float* jw     = (const float*)d_in[3];   // (1024,512) f32
    const float* jb     = (const float*)d_in[4];   // (1024,) f32
    float* out = (float*)d_out;                    // (8,200,100,1024) f32
    unsigned short* wbf = (unsigned short*)d_ws;   // 1 MB bf16 W

    conv_w_kernel<<<512, 256, 0, stream>>>(jw, (ushort4*)wbf);
    joiner_kernel<<<M_TOTAL / M_TILE, 512, 0, stream>>>(enc, prefix, emb, wbf, jb, out);
}